// Round 4
// baseline (237.549 us; speedup 1.0000x reference)
//
#include <hip/hip_runtime.h>
#include <hip/hip_bf16.h>

#define Bn 8
#define Nn 1024
#define Dn 256
#define Hn 4
#define HOn 64
#define Tn 5
#define NEGV -1e9f

typedef short bf16x8 __attribute__((ext_vector_type(8)));
typedef float f32x4 __attribute__((ext_vector_type(4)));

__device__ __forceinline__ float b2f(unsigned short u) {
    unsigned x = ((unsigned)u) << 16;
    float f;
    __builtin_memcpy(&f, &x, 4);
    return f;
}
__device__ __forceinline__ unsigned short f2b(float f) {
    __hip_bfloat16 h = __float2bfloat16(f);
    unsigned short u;
    __builtin_memcpy(&u, &h, 2);
    return u;
}

// ---------- fallback: signal "workspace too small" with out = 100.0 ----------
__global__ __launch_bounds__(256) void k_signal(float* __restrict__ out, int n) {
    int i = blockIdx.x * 256 + threadIdx.x;
    if (i < n) out[i] = 100.0f;
}

// ---------- kernel 0: W [H][D][HO] f32 -> WT [H][HO][D] bf16 ----------
__global__ __launch_bounds__(256) void k_transpose_w(const float* __restrict__ W,
                                                     unsigned short* __restrict__ WT) {
    int idx = blockIdx.x * 256 + threadIdx.x;  // enumerates (h, e, d)
    int d = idx & (Dn - 1);
    int e = (idx >> 8) & (HOn - 1);
    int h = idx >> 14;
    WT[idx] = f2b(W[(size_t)(h * Dn + d) * HOn + e]);
}

// ---------- kernel 1: h = x @ W per head via MFMA; store hT [B][H][HO][N] bf16 ----------
// grid: B * (N/16) blocks of 64 threads (1 wave); 16 rows x 64 e x 4 heads per wave.
__global__ __launch_bounds__(64) void k_proj(const float* __restrict__ X,
                                             const unsigned short* __restrict__ WT,
                                             unsigned short* __restrict__ hT) {
    int lane = threadIdx.x;
    int quad = lane >> 4;
    int l15 = lane & 15;
    int it = blockIdx.x & 63;
    int b = blockIdx.x >> 6;
    int i0 = it * 16;

    // A-frag: A[m=l15][k=quad*8+j]; convert f32 row -> bf16
    bf16x8 Af[8];
    const float* xf = X + ((size_t)(b * Nn + i0 + l15)) * Dn + quad * 8;
#pragma unroll
    for (int kc = 0; kc < 8; kc++) {
        union { bf16x8 v; unsigned short s[8]; } u;
        const float4* xp = (const float4*)(xf + kc * 32);  // 32B-aligned
        float4 A0 = xp[0], A1 = xp[1];
        u.s[0] = f2b(A0.x); u.s[1] = f2b(A0.y); u.s[2] = f2b(A0.z); u.s[3] = f2b(A0.w);
        u.s[4] = f2b(A1.x); u.s[5] = f2b(A1.y); u.s[6] = f2b(A1.z); u.s[7] = f2b(A1.w);
        Af[kc] = u.v;
    }

    for (int h = 0; h < Hn; h++) {
        f32x4 acc[4] = {{0.f, 0.f, 0.f, 0.f}, {0.f, 0.f, 0.f, 0.f},
                        {0.f, 0.f, 0.f, 0.f}, {0.f, 0.f, 0.f, 0.f}};
        const unsigned short* wbase = WT + (size_t)h * HOn * Dn;
#pragma unroll
        for (int kc = 0; kc < 8; kc++) {
#pragma unroll
            for (int et = 0; et < 4; et++) {
                // B[k=quad*8+j][n=l15]: 8 consecutive d at fixed e (WT rows contiguous in d)
                bf16x8 Bf = *(const bf16x8*)(wbase + (size_t)(et * 16 + l15) * Dn + kc * 32 + quad * 8);
                acc[et] = __builtin_amdgcn_mfma_f32_16x16x32_bf16(Af[kc], Bf, acc[et], 0, 0, 0);
            }
        }
        int bh = b * Hn + h;
#pragma unroll
        for (int et = 0; et < 4; et++) {
            int e = et * 16 + l15;
#pragma unroll
            for (int reg = 0; reg < 4; reg++) {
                int i = i0 + quad * 4 + reg;  // C/D: col=lane&15 (=e), row=quad*4+reg (=i)
                hT[((size_t)bh * HOn + e) * Nn + i] = f2b(acc[et][reg]);
            }
        }
    }
}

// ---------- kernel 2: e_src/e_dst [BH][T][N] from hT (coalesced over n) ----------
__global__ __launch_bounds__(256) void k_escore(const unsigned short* __restrict__ hT,
                                                const float* __restrict__ a_src,
                                                const float* __restrict__ a_dst,
                                                float* __restrict__ e_src,
                                                float* __restrict__ e_dst) {
    int bh = blockIdx.x >> 2;  // 32 bh, 4 n-chunks
    int n = (blockIdx.x & 3) * 256 + threadIdx.x;
    int h = bh & (Hn - 1);
    const unsigned short* hb = hT + (size_t)bh * HOn * Nn + n;
    float ss[Tn] = {0.f, 0.f, 0.f, 0.f, 0.f};
    float sd[Tn] = {0.f, 0.f, 0.f, 0.f, 0.f};
#pragma unroll 4
    for (int e = 0; e < HOn; e++) {
        float hv = b2f(hb[(size_t)e * Nn]);
#pragma unroll
        for (int t = 0; t < Tn; t++) {
            ss[t] += hv * a_src[(h * Tn + t) * HOn + e];  // uniform -> scalar load
            sd[t] += hv * a_dst[(h * Tn + t) * HOn + e];
        }
    }
#pragma unroll
    for (int t = 0; t < Tn; t++) {
        e_src[((size_t)bh * Tn + t) * Nn + n] = ss[t];
        e_dst[((size_t)bh * Tn + t) * Nn + n] = sd[t];
    }
}

// ---------- kernel 3: fused flash attention + epilogue ----------
// grid: B * (N/16) blocks of 256 threads; wave w handles head w of the (b, i-tile).
__global__ __launch_bounds__(256) void k_attn(const int* __restrict__ adj,
                                              const float* __restrict__ e_src,
                                              const float* __restrict__ e_dst,
                                              const unsigned short* __restrict__ hT,
                                              const float* __restrict__ bias,
                                              const float* __restrict__ gamma,
                                              const float* __restrict__ beta,
                                              float* __restrict__ out) {
    __shared__ int adj_lds[16][128];                // 8 KB, shared by all 4 waves
    __shared__ unsigned short p_lds[4][16][136];    // per-wave P chunk, bf16, pad 128->136
    __shared__ float m_lds[4][16], l_lds[4][16], a_lds[4][16];
    __shared__ float es_lds[4][Tn][16];

    int tid = threadIdx.x;
    int w = tid >> 6;
    int lane = tid & 63;
    int quad = lane >> 4;
    int l15 = lane & 15;
    int b = blockIdx.x >> 6;
    int i0 = (blockIdx.x & 63) * 16;
    int h = w;
    int bh = b * Hn + h;

    const int* adj_base = adj + ((size_t)(b * Nn + i0)) * Nn;
    const float* edst = e_dst + (size_t)bh * Tn * Nn;
    const unsigned short* hTb = hT + (size_t)bh * HOn * Nn;

    f32x4 acc[4] = {{0.f, 0.f, 0.f, 0.f}, {0.f, 0.f, 0.f, 0.f},
                    {0.f, 0.f, 0.f, 0.f}, {0.f, 0.f, 0.f, 0.f}};

    if (lane < 16) {
        m_lds[w][lane] = -__builtin_inff();
        l_lds[w][lane] = 0.f;
        const float* esrc = e_src + (size_t)bh * Tn * Nn;
#pragma unroll
        for (int t = 0; t < Tn; t++) es_lds[w][t][lane] = esrc[t * Nn + i0 + lane];
    }
    __syncthreads();

    for (int c = 0; c < 8; c++) {
        int jc = c * 128;
        // ---- stage adj chunk [16 rows][128 j] cooperatively (coalesced) ----
#pragma unroll
        for (int k = 0; k < 8; k++) {
            int idx = tid + k * 256;
            int r = idx >> 7;
            int jl = idx & 127;
            adj_lds[r][jl] = adj_base[(size_t)r * Nn + jc + jl];
        }
        __syncthreads();
        // ---- pass 1: scores + online softmax, lanes over j ----
        for (int r = 0; r < 16; r++) {
            float es0 = es_lds[w][0][r], es1 = es_lds[w][1][r], es2 = es_lds[w][2][r];
            float es3 = es_lds[w][3][r], es4 = es_lds[w][4][r];
            float wv[2];
#pragma unroll
            for (int s = 0; s < 2; s++) {
                int jl = s * 64 + lane;
                int a = adj_lds[r][jl];
                int t = a - 1;
                if (t < 0) t = 0;  // clamp; result unused when a==0
                float ed = edst[t * Nn + jc + jl];
                float es = es0;
                es = (t == 1) ? es1 : es;
                es = (t == 2) ? es2 : es;
                es = (t == 3) ? es3 : es;
                es = (t == 4) ? es4 : es;
                float x = es + ed;
                x = (x >= 0.f) ? x : 0.01f * x;  // leaky relu before mask (matches ref)
                wv[s] = (a == 0) ? NEGV : x;
            }
            float mc = fmaxf(wv[0], wv[1]);
#pragma unroll
            for (int off = 32; off; off >>= 1) mc = fmaxf(mc, __shfl_xor(mc, off));
            float m_old = m_lds[w][r];
            float m_new = fmaxf(m_old, mc);
            float alpha = __expf(m_old - m_new);  // first chunk: exp(-inf)=0
            float p0 = __expf(wv[0] - m_new);
            float p1 = __expf(wv[1] - m_new);
            float sum = p0 + p1;
#pragma unroll
            for (int off = 32; off; off >>= 1) sum += __shfl_xor(sum, off);
            if (lane == 0) {
                m_lds[w][r] = m_new;
                l_lds[w][r] = l_lds[w][r] * alpha + sum;
                a_lds[w][r] = alpha;
            }
            p_lds[w][r][lane] = f2b(p0);
            p_lds[w][r][64 + lane] = f2b(p1);
        }
        __syncthreads();
        // ---- rescale accumulators by alpha[row] (C-layout row = quad*4+reg) ----
#pragma unroll
        for (int reg = 0; reg < 4; reg++) {
            float al = a_lds[w][quad * 4 + reg];
#pragma unroll
            for (int et = 0; et < 4; et++) acc[et][reg] *= al;
        }
        // ---- PV via MFMA: A = P (LDS), B = hT (global) ----
#pragma unroll
        for (int k = 0; k < 4; k++) {
            int k0 = k * 32;
            bf16x8 Af = *(const bf16x8*)(&p_lds[w][l15][k0 + quad * 8]);
#pragma unroll
            for (int et = 0; et < 4; et++) {
                bf16x8 Bf = *(const bf16x8*)(hTb + (size_t)(et * 16 + l15) * Nn + jc + k0 + quad * 8);
                acc[et] = __builtin_amdgcn_mfma_f32_16x16x32_bf16(Af, Bf, acc[et], 0, 0, 0);
            }
        }
        __syncthreads();
    }

    // ---- epilogue: /l, +bias, relu, +h (from hT), LayerNorm over HO, store f32 ----
    float bv[4], gv[4], bev[4];
#pragma unroll
    for (int et = 0; et < 4; et++) {
        int e = et * 16 + l15;
        bv[et] = bias[h * HOn + e];
        gv[et] = gamma[h * HOn + e];
        bev[et] = beta[h * HOn + e];
    }
#pragma unroll
    for (int reg = 0; reg < 4; reg++) {
        int r = quad * 4 + reg;
        int i = i0 + r;
        float linv = 1.f / l_lds[w][r];
        float dv[4];
        float s = 0.f, ss = 0.f;
#pragma unroll
        for (int et = 0; et < 4; et++) {
            int e = et * 16 + l15;
            float v = acc[et][reg] * linv + bv[et];
            v = (v > 0.f) ? v : 0.f;
            v += b2f(hTb[(size_t)e * Nn + i]);  // residual h
            dv[et] = v;
            s += v;
            ss += v * v;
        }
#pragma unroll
        for (int off = 8; off; off >>= 1) {
            s += __shfl_xor(s, off);
            ss += __shfl_xor(ss, off);
        }
        float mean = s * (1.f / 64.f);
        float var = ss * (1.f / 64.f) - mean * mean;  // biased, matches torch/jnp
        float rstd = rsqrtf(var + 1e-6f);
#pragma unroll
        for (int et = 0; et < 4; et++) {
            int e = et * 16 + l15;
            float o = (dv[et] - mean) * rstd * gv[et] + bev[et];
            out[((size_t)(b * Nn + i)) * (Hn * HOn) + h * HOn + e] = o;
        }
    }
}

extern "C" void kernel_launch(void* const* d_in, const int* in_sizes, int n_in,
                              void* d_out, int out_size, void* d_ws, size_t ws_size,
                              hipStream_t stream) {
    const float* X = (const float*)d_in[0];        // nodes_embed f32 [B,N,D]
    const int* adj = (const int*)d_in[1];          // node_adj int32 [B,N,N]
    const float* W = (const float*)d_in[2];        // [H,D,HO] f32
    const float* a_src = (const float*)d_in[3];    // [H,T,HO] f32
    const float* a_dst = (const float*)d_in[4];    // [H,T,HO] f32
    const float* bias = (const float*)d_in[5];     // [H,HO] f32
    const float* gamma = (const float*)d_in[6];    // [H,HO] f32
    const float* beta = (const float*)d_in[7];     // [H,HO] f32
    float* out = (float*)d_out;                    // [B,N,H*HO] f32

    // workspace layout: 5,636,096 bytes total (proven available in R3)
    char* ws = (char*)d_ws;
    size_t off = 0;
    unsigned short* hT = (unsigned short*)(ws + off);  off += (size_t)Bn * Hn * Nn * HOn * 2;  // 4 MB
    unsigned short* WT = (unsigned short*)(ws + off);  off += (size_t)Hn * HOn * Dn * 2;       // 128 KB
    float* e_src = (float*)(ws + off);                 off += (size_t)Bn * Hn * Tn * Nn * 4;   // 640 KB
    float* e_dst = (float*)(ws + off);                 off += (size_t)Bn * Hn * Tn * Nn * 4;   // 640 KB

    if (ws_size < off) {
        k_signal<<<(out_size + 255) / 256, 256, 0, stream>>>(out, out_size);
        return;
    }

    k_transpose_w<<<(Hn * HOn * Dn) / 256, 256, 0, stream>>>(W, WT);
    k_proj<<<Bn * (Nn / 16), 64, 0, stream>>>(X, WT, hT);
    k_escore<<<Bn * Hn * (Nn / 256), 256, 0, stream>>>(hT, a_src, a_dst, e_src, e_dst);
    k_attn<<<Bn * (Nn / 16), 256, 0, stream>>>(adj, e_src, e_dst, hT, bias, gamma, beta, out);
}

// Round 5
// 173.275 us; speedup vs baseline: 1.3709x; 1.3709x over previous
//
#include <hip/hip_runtime.h>
#include <hip/hip_bf16.h>

#define Bn 8
#define Nn 1024
#define Dn 256
#define Hn 4
#define HOn 64
#define Tn 5

typedef short bf16x8 __attribute__((ext_vector_type(8)));
typedef float f32x4 __attribute__((ext_vector_type(4)));

__device__ __forceinline__ float b2f(unsigned short u) {
    unsigned x = ((unsigned)u) << 16;
    float f;
    __builtin_memcpy(&f, &x, 4);
    return f;
}
__device__ __forceinline__ unsigned short f2b(float f) {
    __hip_bfloat16 h = __float2bfloat16(f);
    unsigned short u;
    __builtin_memcpy(&u, &h, 2);
    return u;
}

// ---------- fallback: signal "workspace too small" with out = 100.0 ----------
__global__ __launch_bounds__(256) void k_signal(float* __restrict__ out, int n) {
    int i = blockIdx.x * 256 + threadIdx.x;
    if (i < n) out[i] = 100.0f;
}

// ---------- kernel 0: W [H][D][HO] f32 -> WT [H][HO][D] bf16, LDS-tiled ----------
// grid: H * (D/64) = 16 blocks x 256 threads; tile [64 d][64 e] via LDS.
__global__ __launch_bounds__(256) void k_transpose_w(const float* __restrict__ W,
                                                     unsigned short* __restrict__ WT) {
    __shared__ float tile[64][65];
    int h = blockIdx.x >> 2;
    int d0 = (blockIdx.x & 3) * 64;
    int c0 = threadIdx.x & 63;
    int r0 = threadIdx.x >> 6;  // 0..3
#pragma unroll
    for (int r = 0; r < 16; r++) {
        int d = r * 4 + r0;
        tile[d][c0] = W[((size_t)(h * Dn + d0 + d)) * HOn + c0];  // coalesced over e
    }
    __syncthreads();
#pragma unroll
    for (int r = 0; r < 16; r++) {
        int e = r * 4 + r0;
        WT[((size_t)(h * HOn + e)) * Dn + d0 + c0] = f2b(tile[c0][e]);  // coalesced over d
    }
}

// ---------- kernel 1: h = x @ W via MFMA (wave = head) + fused e_src/e_dst ----------
// grid: B * (N/16) blocks x 256 threads; wave w computes head w for the 16-row i-tile.
__global__ __launch_bounds__(256) void k_proj(const float* __restrict__ X,
                                              const unsigned short* __restrict__ WT,
                                              unsigned short* __restrict__ hT,
                                              const float* __restrict__ a_src,
                                              const float* __restrict__ a_dst,
                                              float* __restrict__ e_src,
                                              float* __restrict__ e_dst) {
    int tid = threadIdx.x;
    int w = tid >> 6;
    int lane = tid & 63;
    int quad = lane >> 4;
    int l15 = lane & 15;
    int b = blockIdx.x >> 6;
    int i0 = (blockIdx.x & 63) * 16;
    int h = w;
    int bh = b * Hn + h;

    // A-frag: A[m=l15][k=quad*8+j]; f32 row -> bf16
    bf16x8 Af[8];
    const float* xf = X + ((size_t)(b * Nn + i0 + l15)) * Dn + quad * 8;
#pragma unroll
    for (int kc = 0; kc < 8; kc++) {
        union { bf16x8 v; unsigned short s[8]; } u;
        const float4* xp = (const float4*)(xf + kc * 32);
        float4 A0 = xp[0], A1 = xp[1];
        u.s[0] = f2b(A0.x); u.s[1] = f2b(A0.y); u.s[2] = f2b(A0.z); u.s[3] = f2b(A0.w);
        u.s[4] = f2b(A1.x); u.s[5] = f2b(A1.y); u.s[6] = f2b(A1.z); u.s[7] = f2b(A1.w);
        Af[kc] = u.v;
    }

    f32x4 acc[4] = {{0.f, 0.f, 0.f, 0.f}, {0.f, 0.f, 0.f, 0.f},
                    {0.f, 0.f, 0.f, 0.f}, {0.f, 0.f, 0.f, 0.f}};
    const unsigned short* wbase = WT + (size_t)h * HOn * Dn;
#pragma unroll
    for (int kc = 0; kc < 8; kc++) {
#pragma unroll
        for (int et = 0; et < 4; et++) {
            bf16x8 Bf = *(const bf16x8*)(wbase + (size_t)(et * 16 + l15) * Dn + kc * 32 + quad * 8);
            acc[et] = __builtin_amdgcn_mfma_f32_16x16x32_bf16(Af[kc], Bf, acc[et], 0, 0, 0);
        }
    }

    // store hT [BH][HO][N] bf16 (C/D: col=l15 -> e, row=quad*4+reg -> i)
#pragma unroll
    for (int et = 0; et < 4; et++) {
        int e = et * 16 + l15;
#pragma unroll
        for (int reg = 0; reg < 4; reg++) {
            int i = i0 + quad * 4 + reg;
            hT[((size_t)bh * HOn + e) * Nn + i] = f2b(acc[et][reg]);
        }
    }

    // fused e-scores: e[t][i] = sum_e h[i][e]*a[t][e], from f32 acc (16 h vals/lane)
    float as[Tn][4], ad[Tn][4];
#pragma unroll
    for (int t = 0; t < Tn; t++)
#pragma unroll
        for (int et = 0; et < 4; et++) {
            as[t][et] = a_src[(h * Tn + t) * HOn + et * 16 + l15];
            ad[t][et] = a_dst[(h * Tn + t) * HOn + et * 16 + l15];
        }
#pragma unroll
    for (int reg = 0; reg < 4; reg++) {
        int i = i0 + quad * 4 + reg;
#pragma unroll
        for (int t = 0; t < Tn; t++) {
            float ps = 0.f, pd = 0.f;
#pragma unroll
            for (int et = 0; et < 4; et++) {
                ps += acc[et][reg] * as[t][et];
                pd += acc[et][reg] * ad[t][et];
            }
#pragma unroll
            for (int off = 1; off < 16; off <<= 1) {
                ps += __shfl_xor(ps, off);
                pd += __shfl_xor(pd, off);
            }
            if (l15 == t) {  // 4 lanes (one per quad) hold the group sum
                e_src[((size_t)bh * Tn + t) * Nn + i] = ps;
                e_dst[((size_t)bh * Tn + t) * Nn + i] = pd;
            }
        }
    }
}

// ---------- kernel 2: fused attention (max-free softmax) + epilogue ----------
// grid: B * (N/16) blocks x 256 threads; wave w = head w of the (b, i-tile).
__global__ __launch_bounds__(256) void k_attn(const int* __restrict__ adj,
                                              const float* __restrict__ e_src,
                                              const float* __restrict__ e_dst,
                                              const unsigned short* __restrict__ hT,
                                              const float* __restrict__ bias,
                                              const float* __restrict__ gamma,
                                              const float* __restrict__ beta,
                                              float* __restrict__ out) {
    __shared__ int adj_lds[2][16][128];            // double-buffered, shared by 4 waves
    __shared__ unsigned short p_lds[4][16][136];   // per-wave P chunk (bf16), pad 128->136
    __shared__ float es_lds[4][Tn][16];
    __shared__ float scratch[4][16][68];           // per-wave l-reduction scratch
    __shared__ float l_lds[4][16];

    int tid = threadIdx.x;
    int w = tid >> 6;
    int lane = tid & 63;
    int quad = lane >> 4;
    int l15 = lane & 15;
    int b = blockIdx.x >> 6;
    int i0 = (blockIdx.x & 63) * 16;
    int h = w;
    int bh = b * Hn + h;

    const int* adj_base = adj + ((size_t)(b * Nn + i0)) * Nn;
    const float* edst = e_dst + (size_t)bh * Tn * Nn;
    const unsigned short* hTb = hT + (size_t)bh * HOn * Nn;

    f32x4 acc[4] = {{0.f, 0.f, 0.f, 0.f}, {0.f, 0.f, 0.f, 0.f},
                    {0.f, 0.f, 0.f, 0.f}, {0.f, 0.f, 0.f, 0.f}};
    float pl[16];
#pragma unroll
    for (int r = 0; r < 16; r++) pl[r] = 0.f;

    if (lane < 16) {
        const float* esrc = e_src + (size_t)bh * Tn * Nn;
#pragma unroll
        for (int t = 0; t < Tn; t++) es_lds[w][t][lane] = esrc[t * Nn + i0 + lane];
    }
    // stage adj chunk 0 (all 256 threads)
#pragma unroll
    for (int k = 0; k < 8; k++) {
        int idx = tid + k * 256;
        adj_lds[0][idx >> 7][idx & 127] = adj_base[(size_t)(idx >> 7) * Nn + (idx & 127)];
    }
    // ed chunk 0
    float edc[Tn][2], edn[Tn][2];
#pragma unroll
    for (int t = 0; t < Tn; t++)
#pragma unroll
        for (int s = 0; s < 2; s++) edc[t][s] = edst[t * Nn + s * 64 + lane];
    __syncthreads();

#pragma unroll 1
    for (int c = 0; c < 8; c++) {
        int jc = c * 128;
        int cur = c & 1;
        // prefetch B-frags (hT) for this chunk — consumed after pass 1
        bf16x8 Bf[4][4];
#pragma unroll
        for (int k = 0; k < 4; k++)
#pragma unroll
            for (int et = 0; et < 4; et++)
                Bf[k][et] = *(const bf16x8*)(hTb + (size_t)(et * 16 + l15) * Nn + jc + k * 32 + quad * 8);
        // prefetch next chunk's adj (regs) + ed (regs)
        int anext[8];
        if (c < 7) {
#pragma unroll
            for (int k = 0; k < 8; k++) {
                int idx = tid + k * 256;
                anext[k] = adj_base[(size_t)(idx >> 7) * Nn + jc + 128 + (idx & 127)];
            }
#pragma unroll
            for (int t = 0; t < Tn; t++)
#pragma unroll
                for (int s = 0; s < 2; s++) edn[t][s] = edst[t * Nn + jc + 128 + s * 64 + lane];
        }
        // ---- pass 1: p = exp(leakyrelu(es+ed)) (masked -> 0), no max-subtraction ----
#pragma unroll
        for (int r = 0; r < 16; r++) {
            float es0 = es_lds[w][0][r], es1 = es_lds[w][1][r], es2 = es_lds[w][2][r];
            float es3 = es_lds[w][3][r], es4 = es_lds[w][4][r];
#pragma unroll
            for (int s = 0; s < 2; s++) {
                int a = adj_lds[cur][r][s * 64 + lane];
                float es = es0, ed = edc[0][s];
                bool c2 = (a == 2), c3 = (a == 3), c4 = (a == 4), c5 = (a == 5);
                es = c2 ? es1 : es; ed = c2 ? edc[1][s] : ed;
                es = c3 ? es2 : es; ed = c3 ? edc[2][s] : ed;
                es = c4 ? es3 : es; ed = c4 ? edc[3][s] : ed;
                es = c5 ? es4 : es; ed = c5 ? edc[4][s] : ed;
                float x = es + ed;
                x = fmaxf(x, 0.01f * x);        // leaky relu (valid both signs)
                float p = __expf(x);
                p = (a == 0) ? 0.f : p;         // mask: exp(-1e9) == 0
                pl[r] += p;
                p_lds[w][r][s * 64 + lane] = f2b(p);
            }
        }
        // write prefetched next adj / promote ed
        if (c < 7) {
#pragma unroll
            for (int k = 0; k < 8; k++) {
                int idx = tid + k * 256;
                adj_lds[1 - cur][idx >> 7][idx & 127] = anext[k];
            }
#pragma unroll
            for (int t = 0; t < Tn; t++)
#pragma unroll
                for (int s = 0; s < 2; s++) edc[t][s] = edn[t][s];
        }
        // ---- PV via MFMA: A = P (per-wave LDS, no barrier needed), B = prefetched ----
#pragma unroll
        for (int k = 0; k < 4; k++) {
            bf16x8 Af = *(const bf16x8*)(&p_lds[w][l15][k * 32 + quad * 8]);
#pragma unroll
            for (int et = 0; et < 4; et++)
                acc[et] = __builtin_amdgcn_mfma_f32_16x16x32_bf16(Af, Bf[k][et], acc[et], 0, 0, 0);
        }
        __syncthreads();  // protects adj_lds buffers (one barrier per chunk)
    }

    // ---- deferred l reduction (once): pl[r] summed over 64 lanes via LDS ----
#pragma unroll
    for (int r = 0; r < 16; r++) scratch[w][r][lane] = pl[r];
    float lsum = 0.f;
#pragma unroll
    for (int k = 0; k < 4; k++) {
        f32x4 v = *(const f32x4*)(&scratch[w][l15][quad * 16 + k * 4]);
        lsum += v[0] + v[1] + v[2] + v[3];
    }
    lsum += __shfl_xor(lsum, 16);
    lsum += __shfl_xor(lsum, 32);
    if (quad == 0) l_lds[w][l15] = lsum;  // per-wave array: no block barrier needed

    // ---- epilogue: /l, +bias, relu, +h, LayerNorm over HO, store f32 ----
    float bv[4], gv[4], bev[4];
#pragma unroll
    for (int et = 0; et < 4; et++) {
        int e = et * 16 + l15;
        bv[et] = bias[h * HOn + e];
        gv[et] = gamma[h * HOn + e];
        bev[et] = beta[h * HOn + e];
    }
#pragma unroll
    for (int reg = 0; reg < 4; reg++) {
        int r = quad * 4 + reg;
        int i = i0 + r;
        float linv = 1.f / fmaxf(l_lds[w][r], 1e-30f);
        float dv[4];
        float s = 0.f, ss = 0.f;
#pragma unroll
        for (int et = 0; et < 4; et++) {
            int e = et * 16 + l15;
            float v = acc[et][reg] * linv + bv[et];
            v = (v > 0.f) ? v : 0.f;
            v += b2f(hTb[(size_t)e * Nn + i]);  // residual h
            dv[et] = v;
            s += v;
            ss += v * v;
        }
#pragma unroll
        for (int off = 8; off; off >>= 1) {
            s += __shfl_xor(s, off);
            ss += __shfl_xor(ss, off);
        }
        float mean = s * (1.f / 64.f);
        float var = ss * (1.f / 64.f) - mean * mean;
        float rstd = rsqrtf(var + 1e-6f);
#pragma unroll
        for (int et = 0; et < 4; et++) {
            int e = et * 16 + l15;
            float o = (dv[et] - mean) * rstd * gv[et] + bev[et];
            out[((size_t)(b * Nn + i)) * (Hn * HOn) + h * HOn + e] = o;
        }
    }
}

extern "C" void kernel_launch(void* const* d_in, const int* in_sizes, int n_in,
                              void* d_out, int out_size, void* d_ws, size_t ws_size,
                              hipStream_t stream) {
    const float* X = (const float*)d_in[0];        // nodes_embed f32 [B,N,D]
    const int* adj = (const int*)d_in[1];          // node_adj int32 [B,N,N]
    const float* W = (const float*)d_in[2];        // [H,D,HO] f32
    const float* a_src = (const float*)d_in[3];    // [H,T,HO] f32
    const float* a_dst = (const float*)d_in[4];    // [H,T,HO] f32
    const float* bias = (const float*)d_in[5];     // [H,HO] f32
    const float* gamma = (const float*)d_in[6];    // [H,HO] f32
    const float* beta = (const float*)d_in[7];     // [H,HO] f32
    float* out = (float*)d_out;                    // [B,N,H*HO] f32

    char* ws = (char*)d_ws;
    size_t off = 0;
    unsigned short* hT = (unsigned short*)(ws + off);  off += (size_t)Bn * Hn * Nn * HOn * 2;  // 4 MB
    unsigned short* WT = (unsigned short*)(ws + off);  off += (size_t)Hn * HOn * Dn * 2;       // 128 KB
    float* e_src = (float*)(ws + off);                 off += (size_t)Bn * Hn * Tn * Nn * 4;   // 640 KB
    float* e_dst = (float*)(ws + off);                 off += (size_t)Bn * Hn * Tn * Nn * 4;   // 640 KB

    if (ws_size < off) {
        k_signal<<<(out_size + 255) / 256, 256, 0, stream>>>(out, out_size);
        return;
    }

    k_transpose_w<<<Hn * (Dn / 64), 256, 0, stream>>>(W, WT);
    k_proj<<<Bn * (Nn / 16), 256, 0, stream>>>(X, WT, hT, a_src, a_dst, e_src, e_dst);
    k_attn<<<Bn * (Nn / 16), 256, 0, stream>>>(adj, e_src, e_dst, hT, bias, gamma, beta, out);
}

// Round 6
// 162.252 us; speedup vs baseline: 1.4641x; 1.0679x over previous
//
#include <hip/hip_runtime.h>
#include <hip/hip_bf16.h>

#define Bn 8
#define Nn 1024
#define Dn 256
#define Hn 4
#define HOn 64
#define Tn 5
#define WTR 80   // WT rows per head: 64 h-cols + 10 e-score cols + 6 pad

typedef short bf16x8 __attribute__((ext_vector_type(8)));
typedef float f32x4 __attribute__((ext_vector_type(4)));

__device__ __forceinline__ float b2f(unsigned short u) {
    unsigned x = ((unsigned)u) << 16;
    float f;
    __builtin_memcpy(&f, &x, 4);
    return f;
}
// fast RNE f32->bf16 (finite inputs only)
__device__ __forceinline__ unsigned bfr(float f) {
    unsigned u;
    __builtin_memcpy(&u, &f, 4);
    return (u + 0x7FFFu + ((u >> 16) & 1u)) >> 16;
}
__device__ __forceinline__ unsigned short f2b(float f) { return (unsigned short)bfr(f); }

// ---------- fallback: signal "workspace too small" with out = 100.0 ----------
__global__ __launch_bounds__(256) void k_signal(float* __restrict__ out, int n) {
    int i = blockIdx.x * 256 + threadIdx.x;
    if (i < n) out[i] = 100.0f;
}

// ---------- kernel 0: WT [H][80][D] bf16: rows 0-63 = W^T, 64-73 = W.a_src|W.a_dst, 74-79 = 0
// grid: H * (D/64) = 16 blocks x 256 threads.
__global__ __launch_bounds__(256) void k_transpose_w(const float* __restrict__ W,
                                                     const float* __restrict__ a_src,
                                                     const float* __restrict__ a_dst,
                                                     unsigned short* __restrict__ WT) {
    __shared__ float tile[64][65];
    int h = blockIdx.x >> 2;
    int d0 = (blockIdx.x & 3) * 64;
    int c0 = threadIdx.x & 63;
    int r0 = threadIdx.x >> 6;  // 0..3
#pragma unroll
    for (int r = 0; r < 16; r++) {
        int d = r * 4 + r0;
        tile[d][c0] = W[((size_t)(h * Dn + d0 + d)) * HOn + c0];  // coalesced over e
    }
    __syncthreads();
    // W^T rows (coalesced over d)
#pragma unroll
    for (int r = 0; r < 16; r++) {
        int e = r * 4 + r0;
        WT[((size_t)(h * WTR + e)) * Dn + d0 + c0] = f2b(tile[c0][e]);
    }
    // Wa rows: row 64+t = sum_e W[d][e] * a[t][e]  (t<5: a_src, else a_dst)
    for (int t = r0; t < 2 * Tn; t += 4) {
        const float* av = (t < Tn) ? (a_src + (h * Tn + t) * HOn)
                                   : (a_dst + (h * Tn + t - Tn) * HOn);
        float s = 0.f;
#pragma unroll
        for (int e = 0; e < HOn; e++) s += tile[c0][e] * av[e];
        WT[((size_t)(h * WTR + 64 + t)) * Dn + d0 + c0] = f2b(s);
    }
    // zero pad rows 74..79
    for (int rr = 74 + r0; rr < WTR; rr += 4)
        WT[((size_t)(h * WTR + rr)) * Dn + d0 + c0] = 0;
}

// ---------- kernel 1: h = x @ W via MFMA (wave = head); 5th tile = e-scores ----------
// grid: B * (N/16) blocks x 256 threads.
__global__ __launch_bounds__(256) void k_proj(const float* __restrict__ X,
                                              const unsigned short* __restrict__ WT,
                                              unsigned short* __restrict__ hT,
                                              float* __restrict__ e_src,
                                              float* __restrict__ e_dst) {
    int tid = threadIdx.x;
    int w = tid >> 6;
    int lane = tid & 63;
    int quad = lane >> 4;
    int l15 = lane & 15;
    int b = blockIdx.x >> 6;
    int i0 = (blockIdx.x & 63) * 16;
    int h = w;
    int bh = b * Hn + h;

    // A-frag: A[m=l15][k=quad*8+j]; f32 row -> bf16
    bf16x8 Af[8];
    const float* xf = X + ((size_t)(b * Nn + i0 + l15)) * Dn + quad * 8;
#pragma unroll
    for (int kc = 0; kc < 8; kc++) {
        union { bf16x8 v; unsigned short s[8]; } u;
        const float4* xp = (const float4*)(xf + kc * 32);
        float4 A0 = xp[0], A1 = xp[1];
        u.s[0] = f2b(A0.x); u.s[1] = f2b(A0.y); u.s[2] = f2b(A0.z); u.s[3] = f2b(A0.w);
        u.s[4] = f2b(A1.x); u.s[5] = f2b(A1.y); u.s[6] = f2b(A1.z); u.s[7] = f2b(A1.w);
        Af[kc] = u.v;
    }

    f32x4 acc[5] = {{0.f, 0.f, 0.f, 0.f}, {0.f, 0.f, 0.f, 0.f}, {0.f, 0.f, 0.f, 0.f},
                    {0.f, 0.f, 0.f, 0.f}, {0.f, 0.f, 0.f, 0.f}};
    const unsigned short* wbase = WT + (size_t)h * WTR * Dn;
#pragma unroll
    for (int kc = 0; kc < 8; kc++) {
#pragma unroll
        for (int et = 0; et < 5; et++) {
            bf16x8 Bf = *(const bf16x8*)(wbase + (size_t)(et * 16 + l15) * Dn + kc * 32 + quad * 8);
            acc[et] = __builtin_amdgcn_mfma_f32_16x16x32_bf16(Af[kc], Bf, acc[et], 0, 0, 0);
        }
    }

    // store hT [BH][HO][N] bf16 (C/D: col=l15 -> e, row=quad*4+reg -> i)
#pragma unroll
    for (int et = 0; et < 4; et++) {
        int e = et * 16 + l15;
#pragma unroll
        for (int reg = 0; reg < 4; reg++) {
            int i = i0 + quad * 4 + reg;
            hT[((size_t)bh * HOn + e) * Nn + i] = f2b(acc[et][reg]);
        }
    }
    // 5th tile: col l15 = t (0-4: e_src, 5-9: e_dst)
#pragma unroll
    for (int reg = 0; reg < 4; reg++) {
        int i = i0 + quad * 4 + reg;
        if (l15 < Tn)
            e_src[((size_t)bh * Tn + l15) * Nn + i] = acc[4][reg];
        else if (l15 < 2 * Tn)
            e_dst[((size_t)bh * Tn + (l15 - Tn)) * Nn + i] = acc[4][reg];
    }
}

// ---------- kernel 2: fused attention, barrier-free main loop ----------
// grid: B * (N/16) blocks x 512 threads (8 waves); wave = (head = w&3, j-half = w>>2).
__global__ __launch_bounds__(512) void k_attn(const int* __restrict__ adj,
                                              const float* __restrict__ e_src,
                                              const float* __restrict__ e_dst,
                                              const unsigned short* __restrict__ hT,
                                              const float* __restrict__ bias,
                                              const float* __restrict__ gamma,
                                              const float* __restrict__ beta,
                                              float* __restrict__ out) {
    __shared__ unsigned short p_lds[8][16][140];  // per-wave P chunk (bf16), stride 140
    __shared__ float macc[4][16][64];             // j-half merge area
    __shared__ float es_lds[4][Tn][16];
    __shared__ float l_lds[8][16];

    int tid = threadIdx.x;
    int w = tid >> 6;
    int lane = tid & 63;
    int quad = lane >> 4;
    int l15 = lane & 15;
    int hh = w & 3;
    int half = w >> 2;
    int b = blockIdx.x >> 6;
    int i0 = (blockIdx.x & 63) * 16;
    int bh = b * Hn + hh;

    const int* adj_base = adj + ((size_t)(b * Nn + i0)) * Nn;
    const float* edst = e_dst + (size_t)bh * Tn * Nn;
    const unsigned short* hTb = hT + (size_t)bh * HOn * Nn;
    int J0 = half * 512;

    f32x4 acc[4] = {{0.f, 0.f, 0.f, 0.f}, {0.f, 0.f, 0.f, 0.f},
                    {0.f, 0.f, 0.f, 0.f}, {0.f, 0.f, 0.f, 0.f}};
    float pl[16];
#pragma unroll
    for (int r = 0; r < 16; r++) pl[r] = 0.f;

    if (w < 4 && lane < 16) {
        const float* esrc = e_src + (size_t)bh * Tn * Nn;
#pragma unroll
        for (int t = 0; t < Tn; t++) es_lds[w][t][lane] = esrc[t * Nn + i0 + lane];
    }
    __syncthreads();

    // ed chunk 0 (lane covers j = J0 + 2*lane, 2*lane+1)
    float2 edc[Tn], edn[Tn];
#pragma unroll
    for (int t = 0; t < Tn; t++) edc[t] = *(const float2*)(edst + t * Nn + J0 + 2 * lane);

#pragma unroll 1
    for (int c = 0; c < 4; c++) {
        int jc = J0 + c * 128;
        if (c < 3) {
#pragma unroll
            for (int t = 0; t < Tn; t++) edn[t] = *(const float2*)(edst + t * Nn + jc + 128 + 2 * lane);
        }
        // ---- pass 1: p = exp(leakyrelu(es+ed)), masked -> 0; adj straight from global ----
#pragma unroll
        for (int r = 0; r < 16; r++) {
            int2 av = *(const int2*)(adj_base + (size_t)r * Nn + jc + 2 * lane);
            float es0 = es_lds[hh][0][r], es1 = es_lds[hh][1][r], es2 = es_lds[hh][2][r];
            float es3 = es_lds[hh][3][r], es4 = es_lds[hh][4][r];
            float p01[2];
            int aa[2] = {av.x, av.y};
#pragma unroll
            for (int s = 0; s < 2; s++) {
                int a = aa[s];
                bool c2 = (a == 2), c3 = (a == 3), c4 = (a == 4), c5 = (a == 5);
                float es = es0, ed = (s == 0) ? edc[0].x : edc[0].y;
                es = c2 ? es1 : es; ed = c2 ? ((s == 0) ? edc[1].x : edc[1].y) : ed;
                es = c3 ? es2 : es; ed = c3 ? ((s == 0) ? edc[2].x : edc[2].y) : ed;
                es = c4 ? es3 : es; ed = c4 ? ((s == 0) ? edc[3].x : edc[3].y) : ed;
                es = c5 ? es4 : es; ed = c5 ? ((s == 0) ? edc[4].x : edc[4].y) : ed;
                float x = es + ed;
                x = fmaxf(x, 0.01f * x);       // leaky relu
                float p = __expf(x);
                p = (a == 0) ? 0.f : p;        // mask
                pl[r] += p;
                p01[s] = p;
            }
            *(unsigned*)(&p_lds[w][r][2 * lane]) = bfr(p01[0]) | (bfr(p01[1]) << 16);
        }
        // promote prefetched ed
        if (c < 3) {
#pragma unroll
            for (int t = 0; t < Tn; t++) edc[t] = edn[t];
        }
        // ---- PV via MFMA: A = P (own-wave LDS), B = hT (L2-hot), no barrier ----
#pragma unroll
        for (int k = 0; k < 4; k++) {
            bf16x8 Afr = *(const bf16x8*)(&p_lds[w][l15][k * 32 + quad * 8]);
#pragma unroll
            for (int et = 0; et < 4; et++) {
                bf16x8 Bf = *(const bf16x8*)(hTb + (size_t)(et * 16 + l15) * Nn + jc + k * 32 + quad * 8);
                acc[et] = __builtin_amdgcn_mfma_f32_16x16x32_bf16(Afr, Bf, acc[et], 0, 0, 0);
            }
        }
    }

    // ---- per-wave l reduction (once): butterfly over 64 lanes ----
#pragma unroll
    for (int r = 0; r < 16; r++) {
#pragma unroll
        for (int off = 1; off < 64; off <<= 1) pl[r] += __shfl_xor(pl[r], off);
    }
    if (lane == 0) {
#pragma unroll
        for (int r = 0; r < 16; r++) l_lds[w][r] = pl[r];
    }
    // j-half 1 publishes its accumulator
    if (w >= 4) {
#pragma unroll
        for (int et = 0; et < 4; et++)
#pragma unroll
            for (int reg = 0; reg < 4; reg++)
                macc[hh][quad * 4 + reg][et * 16 + l15] = acc[et][reg];
    }
    __syncthreads();
    if (w >= 4) return;

    // ---- merge + epilogue: /l, +bias, relu, +h, LayerNorm over HO, store f32 ----
    float bv[4], gv[4], bev[4];
#pragma unroll
    for (int et = 0; et < 4; et++) {
        int e = et * 16 + l15;
        bv[et] = bias[hh * HOn + e];
        gv[et] = gamma[hh * HOn + e];
        bev[et] = beta[hh * HOn + e];
    }
#pragma unroll
    for (int reg = 0; reg < 4; reg++) {
        int r = quad * 4 + reg;
        int i = i0 + r;
        float lw = l_lds[w][r] + l_lds[w + 4][r];
        float linv = 1.f / fmaxf(lw, 1e-30f);
        float dv[4];
        float s = 0.f, ss = 0.f;
#pragma unroll
        for (int et = 0; et < 4; et++) {
            int e = et * 16 + l15;
            float v = (acc[et][reg] + macc[hh][r][e]) * linv + bv[et];
            v = (v > 0.f) ? v : 0.f;
            v += b2f(hTb[(size_t)e * Nn + i]);  // residual h
            dv[et] = v;
            s += v;
            ss += v * v;
        }
#pragma unroll
        for (int off = 8; off; off >>= 1) {
            s += __shfl_xor(s, off);
            ss += __shfl_xor(ss, off);
        }
        float mean = s * (1.f / 64.f);
        float var = ss * (1.f / 64.f) - mean * mean;
        float rstd = rsqrtf(var + 1e-6f);
#pragma unroll
        for (int et = 0; et < 4; et++) {
            int e = et * 16 + l15;
            float o = (dv[et] - mean) * rstd * gv[et] + bev[et];
            out[((size_t)(b * Nn + i)) * (Hn * HOn) + hh * HOn + e] = o;
        }
    }
}

extern "C" void kernel_launch(void* const* d_in, const int* in_sizes, int n_in,
                              void* d_out, int out_size, void* d_ws, size_t ws_size,
                              hipStream_t stream) {
    const float* X = (const float*)d_in[0];        // nodes_embed f32 [B,N,D]
    const int* adj = (const int*)d_in[1];          // node_adj int32 [B,N,N]
    const float* W = (const float*)d_in[2];        // [H,D,HO] f32
    const float* a_src = (const float*)d_in[3];    // [H,T,HO] f32
    const float* a_dst = (const float*)d_in[4];    // [H,T,HO] f32
    const float* bias = (const float*)d_in[5];     // [H,HO] f32
    const float* gamma = (const float*)d_in[6];    // [H,HO] f32
    const float* beta = (const float*)d_in[7];     // [H,HO] f32
    float* out = (float*)d_out;                    // [B,N,H*HO] f32

    char* ws = (char*)d_ws;
    size_t off = 0;
    unsigned short* hT = (unsigned short*)(ws + off);  off += (size_t)Bn * Hn * Nn * HOn * 2;  // 4 MB
    unsigned short* WT = (unsigned short*)(ws + off);  off += (size_t)Hn * WTR * Dn * 2;       // 160 KB
    float* e_src = (float*)(ws + off);                 off += (size_t)Bn * Hn * Tn * Nn * 4;   // 640 KB
    float* e_dst = (float*)(ws + off);                 off += (size_t)Bn * Hn * Tn * Nn * 4;   // 640 KB

    if (ws_size < off) {
        k_signal<<<(out_size + 255) / 256, 256, 0, stream>>>(out, out_size);
        return;
    }

    k_transpose_w<<<Hn * (Dn / 64), 256, 0, stream>>>(W, a_src, a_dst, WT);
    k_proj<<<Bn * (Nn / 16), 256, 0, stream>>>(X, WT, hT, e_src, e_dst);
    k_attn<<<Bn * (Nn / 16), 512, 0, stream>>>(adj, e_src, e_dst, hT, bias, gamma, beta, out);
}